// Round 2
// baseline (269.906 us; speedup 1.0000x reference)
//
#include <hip/hip_runtime.h>

using short8   = __attribute__((ext_vector_type(8))) short;
using f32x4    = __attribute__((ext_vector_type(4))) float;
using ushort4v = __attribute__((ext_vector_type(4))) unsigned short;

#define BN_EPS    1e-5f
#define ATT_SCALE 0.17677669529663687f   // 1/sqrt(32), folded into q projection

__device__ __forceinline__ unsigned short f2bf(float f) {
    union { float f; unsigned u; } v; v.f = f;
    return (unsigned short)((v.u + 0x7FFFu + ((v.u >> 16) & 1u)) >> 16);  // RNE
}

// pack two f32 -> two bf16 (round-half-up) in ONE v_perm + 2 adds
__device__ __forceinline__ unsigned pack2bf(float a, float b) {
    union { float f; unsigned u; } ua, ub; ua.f = a; ub.f = b;
    return __builtin_amdgcn_perm(ub.u + 0x8000u, ua.u + 0x8000u, 0x07060302u);
}

// ---------------------------------------------------------------------------
// Kernel 0: weights -> bf16; fold conv-bias + BN into per-row (scale, offset).
// Rows: 0-31 q, 32-63 k, 64-319 v.
// ---------------------------------------------------------------------------
__global__ void prep_kernel(
    const float* __restrict__ qw, const float* __restrict__ qb,
    const float* __restrict__ qg, const float* __restrict__ qbe,
    const float* __restrict__ qm, const float* __restrict__ qv,
    const float* __restrict__ kw, const float* __restrict__ kb,
    const float* __restrict__ kg, const float* __restrict__ kbe,
    const float* __restrict__ km, const float* __restrict__ kvv,
    const float* __restrict__ vw, const float* __restrict__ vb,
    const float* __restrict__ vg, const float* __restrict__ vbe,
    const float* __restrict__ vm, const float* __restrict__ vv,
    unsigned short* __restrict__ wq, float* __restrict__ scale,
    float* __restrict__ off)
{
    int r = blockIdx.x;      // 0..319
    int t = threadIdx.x;     // 0..63
    const float *wsrc, *g, *be, *mn, *vr, *bi;
    int rl;
    if (r < 32)      { rl = r;      wsrc = qw; g = qg; be = qbe; mn = qm; vr = qv;  bi = qb; }
    else if (r < 64) { rl = r - 32; wsrc = kw; g = kg; be = kbe; mn = km; vr = kvv; bi = kb; }
    else             { rl = r - 64; wsrc = vw; g = vg; be = vbe; mn = vm; vr = vv;  bi = vb; }

    float4 w4 = *(const float4*)(wsrc + rl * 256 + t * 4);
    ushort4v o;
    o.x = f2bf(w4.x); o.y = f2bf(w4.y); o.z = f2bf(w4.z); o.w = f2bf(w4.w);
    *(ushort4v*)(wq + r * 256 + t * 4) = o;

    if (t == 0) {
        float inv = g[rl] * rsqrtf(vr[rl] + BN_EPS);
        float ofv = bi[rl] * inv + be[rl] - mn[rl] * inv;
        float s = (r < 32) ? ATT_SCALE : 1.0f;
        scale[r] = inv * s;
        off[r]   = ofv * s;
    }
}

// ---------------------------------------------------------------------------
// Kernel 1: projections. bx = (b*64+nt)*3 + g ; g=0: q(x1), g=1: k(x2),
// g=2: ALL 256 v rows (x2) -> x2 staged twice total instead of 5 times.
// Xt pitch 264 shorts: b128 reads are bank-uniform (structural 8/bank).
// ---------------------------------------------------------------------------
#define XT_PITCH 264

__global__ __launch_bounds__(256) void proj_kernel(
    const float* __restrict__ x1, const float* __restrict__ x2,
    const unsigned short* __restrict__ wq,
    const float* __restrict__ scale, const float* __restrict__ off,
    unsigned short* __restrict__ q_t, unsigned short* __restrict__ k_t,
    unsigned short* __restrict__ v_bf)
{
    __shared__ unsigned short Xt[64 * XT_PITCH];   // 33792 B
    int bx = blockIdx.x;
    int g  = bx % 3;
    int t2 = bx / 3;
    int nt = t2 & 63;
    int b  = t2 >> 6;
    int n0 = nt * 64;
    int tid = threadIdx.x;
    int wv = tid >> 6, lane = tid & 63;
    int m16 = lane & 15, qd = lane >> 4;

    const float* xb = ((g == 0) ? x1 : x2) + (size_t)b * 256 * 4096;

    #pragma unroll
    for (int i = 0; i < 8; ++i) {
        int p  = i * 256 + tid;
        int c2 = p >> 4;
        int u4 = (p & 15) * 4;
        float4 a = *(const float4*)(xb + (size_t)(2 * c2)     * 4096 + n0 + u4);
        float4 c = *(const float4*)(xb + (size_t)(2 * c2 + 1) * 4096 + n0 + u4);
        float av[4] = {a.x, a.y, a.z, a.w};
        float cv[4] = {c.x, c.y, c.z, c.w};
        #pragma unroll
        for (int u = 0; u < 4; ++u) {
            unsigned pk = (unsigned)f2bf(av[u]) | ((unsigned)f2bf(cv[u]) << 16);
            *(unsigned*)&Xt[(u4 + u) * XT_PITCH + 2 * c2] = pk;
        }
    }
    __syncthreads();

    f32x4 zero4 = {0.f, 0.f, 0.f, 0.f};

    if (g < 2) {
        int rb = g * 32;
        f32x4 acc0 = zero4, acc1 = zero4;
        #pragma unroll
        for (int s = 0; s < 8; ++s) {
            short8 w0 = *(const short8*)(wq + (size_t)(rb +      m16) * 256 + s * 32 + qd * 8);
            short8 w1 = *(const short8*)(wq + (size_t)(rb + 16 + m16) * 256 + s * 32 + qd * 8);
            short8 xf = *(const short8*)&Xt[(16 * wv + m16) * XT_PITCH + s * 32 + qd * 8];
            acc0 = __builtin_amdgcn_mfma_f32_16x16x32_bf16(w0, xf, acc0, 0, 0, 0);
            acc1 = __builtin_amdgcn_mfma_f32_16x16x32_bf16(w1, xf, acc1, 0, 0, 0);
        }
        unsigned short* dst = (g == 0) ? q_t : k_t;
        int ncol = n0 + 16 * wv + m16;
        #pragma unroll
        for (int tm = 0; tm < 2; ++tm) {
            f32x4 acc = tm ? acc1 : acc0;
            int r0 = 16 * tm + 4 * qd;
            float4 sc = *(const float4*)(scale + rb + r0);
            float4 of = *(const float4*)(off   + rb + r0);
            ushort4v o;
            o.x = f2bf(acc.x * sc.x + of.x);
            o.y = f2bf(acc.y * sc.y + of.y);
            o.z = f2bf(acc.z * sc.z + of.z);
            o.w = f2bf(acc.w * sc.w + of.w);
            *(ushort4v*)(dst + ((size_t)b * 4096 + ncol) * 32 + r0) = o;
        }
    } else {
        f32x4 acc[4][4];
        #pragma unroll
        for (int rr = 0; rr < 4; ++rr)
            #pragma unroll
            for (int tm = 0; tm < 4; ++tm) acc[rr][tm] = zero4;
        #pragma unroll
        for (int s = 0; s < 8; ++s) {
            short8 xf[4];
            #pragma unroll
            for (int tm = 0; tm < 4; ++tm)
                xf[tm] = *(const short8*)&Xt[(16 * tm + m16) * XT_PITCH + s * 32 + qd * 8];
            #pragma unroll
            for (int rr = 0; rr < 4; ++rr) {
                short8 wf = *(const short8*)(wq + (size_t)(64 + rr * 64 + 16 * wv + m16) * 256 + s * 32 + qd * 8);
                #pragma unroll
                for (int tm = 0; tm < 4; ++tm)
                    acc[rr][tm] = __builtin_amdgcn_mfma_f32_16x16x32_bf16(xf[tm], wf, acc[rr][tm], 0, 0, 0);
            }
        }
        #pragma unroll
        for (int rr = 0; rr < 4; ++rr) {
            int rglob = 64 + rr * 64 + 16 * wv + m16;
            int c = rglob - 64;
            float sc = scale[rglob], of = off[rglob];
            #pragma unroll
            for (int tm = 0; tm < 4; ++tm) {
                int nloc = 16 * tm + 4 * qd;
                ushort4v o;
                o.x = f2bf(acc[rr][tm].x * sc + of);
                o.y = f2bf(acc[rr][tm].y * sc + of);
                o.z = f2bf(acc[rr][tm].z * sc + of);
                o.w = f2bf(acc[rr][tm].w * sc + of);
                *(ushort4v*)(v_bf + ((size_t)b * 256 + c) * 4096 + n0 + nloc) = o;
            }
        }
    }
}

// ---------------------------------------------------------------------------
// Kernel 2: BARRIER-FREE flash attention.
// Wave = 32 queries x 64 channels x all 4096 keys. 2048 waves = 512 blocks
// of 4 waves = 2 blocks/CU. S^T trick (A=K, B=Q) => P exchange is wave-
// private LDS (same-wave lgkmcnt dependency only, no __syncthreads).
// bx%8 == b*4+cg => each XCD's L2 keeps its (b,cg) K/V set (~1.6MB) resident.
// ---------------------------------------------------------------------------
#define PP 72                      // P pitch (shorts): 16B-aligned rows, bank-uniform

__global__ __launch_bounds__(256, 2) void flash_kernel(
    const unsigned short* __restrict__ q_t, const unsigned short* __restrict__ k_t,
    const unsigned short* __restrict__ v_bf, float* __restrict__ out)
{
    __shared__ unsigned short Plds[4 * 2 * 32 * PP];   // 36864 B (4 waves x dbuf)

    int bx  = blockIdx.x;
    int cg  = bx & 3;
    int b   = (bx >> 2) & 3;
    int qtg = bx >> 4;             // 0..31
    int tid = threadIdx.x;
    int wv = tid >> 6, lane = tid & 63;
    int m16 = lane & 15, qd = lane >> 4;

    int q0 = qtg * 128 + wv * 32;
    int c0 = cg * 64;

    const unsigned short* qb = q_t + (size_t)b * 4096 * 32;
    const unsigned short* kb = k_t + (size_t)b * 4096 * 32;
    const unsigned short* vb = v_bf + ((size_t)b * 256 + c0) * 4096;

    short8 Qf0 = *(const short8*)(qb + (size_t)(q0 +      m16) * 32 + qd * 8);
    short8 Qf1 = *(const short8*)(qb + (size_t)(q0 + 16 + m16) * 32 + qd * 8);

    f32x4 zero4 = {0.f, 0.f, 0.f, 0.f};
    f32x4 acc[2][4];
    #pragma unroll
    for (int mt = 0; mt < 2; ++mt)
        #pragma unroll
        for (int cs = 0; cs < 4; ++cs) acc[mt][cs] = zero4;
    float lsum0 = 0.f, lsum1 = 0.f;

    unsigned short* Pbase = &Plds[wv * (2 * 32 * PP)];

    #pragma unroll 2
    for (int it = 0; it < 64; ++it) {
        int kt = (it + qtg * 2) & 63;      // staggered start spreads L2 demand
        int n0 = kt * 64;
        unsigned short* Pw = Pbase + (it & 1) * (32 * PP);

        // ---- global loads (independent; issue early) ----
        short8 Kf[4];
        #pragma unroll
        for (int s = 0; s < 4; ++s)
            Kf[s] = *(const short8*)(kb + (size_t)(n0 + s * 16 + m16) * 32 + qd * 8);
        short8 Vf[4][2];
        #pragma unroll
        for (int cs = 0; cs < 4; ++cs)
            #pragma unroll
            for (int t = 0; t < 2; ++t)
                Vf[cs][t] = *(const short8*)(vb + (size_t)(cs * 16 + m16) * 4096 + n0 + t * 32 + qd * 8);

        // ---- S^T = K.Q^T : col=query, row(=reg)=key (4 consecutive keys/lane)
        f32x4 St0[4], St1[4];
        #pragma unroll
        for (int s = 0; s < 4; ++s) {
            St0[s] = __builtin_amdgcn_mfma_f32_16x16x32_bf16(Kf[s], Qf0, zero4, 0, 0, 0);
            St1[s] = __builtin_amdgcn_mfma_f32_16x16x32_bf16(Kf[s], Qf1, zero4, 0, 0, 0);
        }

        // ---- exp + pack + wave-private P write (no barrier) ----
        #pragma unroll
        for (int s = 0; s < 4; ++s) {
            float a0 = __expf(St0[s].x), a1 = __expf(St0[s].y);
            float a2 = __expf(St0[s].z), a3 = __expf(St0[s].w);
            lsum0 += (a0 + a1) + (a2 + a3);
            uint2 w0; w0.x = pack2bf(a0, a1); w0.y = pack2bf(a2, a3);
            *(uint2*)&Pw[(     m16) * PP + s * 16 + qd * 4] = w0;
            float b0 = __expf(St1[s].x), b1 = __expf(St1[s].y);
            float b2 = __expf(St1[s].z), b3 = __expf(St1[s].w);
            lsum1 += (b0 + b1) + (b2 + b3);
            uint2 w1; w1.x = pack2bf(b0, b1); w1.y = pack2bf(b2, b3);
            *(uint2*)&Pw[(16 + m16) * PP + s * 16 + qd * 4] = w1;
        }

        // ---- read own A-frags back (lgkmcnt wait auto-inserted) ----
        short8 Ap[2][2];
        #pragma unroll
        for (int mt = 0; mt < 2; ++mt)
            #pragma unroll
            for (int t = 0; t < 2; ++t)
                Ap[mt][t] = *(const short8*)&Pw[(mt * 16 + m16) * PP + t * 32 + qd * 8];

        // ---- PV: D[query][channel] ----
        #pragma unroll
        for (int t = 0; t < 2; ++t)
            #pragma unroll
            for (int cs = 0; cs < 4; ++cs) {
                acc[0][cs] = __builtin_amdgcn_mfma_f32_16x16x32_bf16(Ap[0][t], Vf[cs][t], acc[0][cs], 0, 0, 0);
                acc[1][cs] = __builtin_amdgcn_mfma_f32_16x16x32_bf16(Ap[1][t], Vf[cs][t], acc[1][cs], 0, 0, 0);
            }
    }

    // ---- softmax denominators: reduce over the 4 qd lanes per query ----
    lsum0 += __shfl_xor(lsum0, 16); lsum0 += __shfl_xor(lsum0, 32);
    lsum1 += __shfl_xor(lsum1, 16); lsum1 += __shfl_xor(lsum1, 32);
    float li0 = 1.0f / lsum0;     // valid for query m16      (mt=0)
    float li1 = 1.0f / lsum1;     // valid for query 16+m16   (mt=1)

    // per-output-row l: rows of acc are queries mt*16 + qd*4 + r
    float lr[2][4];
    #pragma unroll
    for (int r = 0; r < 4; ++r) {
        lr[0][r] = __shfl(li0, 4 * qd + r);
        lr[1][r] = __shfl(li1, 4 * qd + r);
    }

    float* ob = out + ((size_t)b * 256 + c0) * 4096 + q0;
    #pragma unroll
    for (int mt = 0; mt < 2; ++mt)
        #pragma unroll
        for (int cs = 0; cs < 4; ++cs) {
            float4 o;
            o.x = acc[mt][cs].x * lr[mt][0];
            o.y = acc[mt][cs].y * lr[mt][1];
            o.z = acc[mt][cs].z * lr[mt][2];
            o.w = acc[mt][cs].w * lr[mt][3];
            *(float4*)(ob + (size_t)(cs * 16 + m16) * 4096 + mt * 16 + qd * 4) = o;
        }
}

// ---------------------------------------------------------------------------
// Workspace: wq 320x256 bf16 | scale/off 320 f32 | q_t,k_t [b][n][32] bf16 |
// v_bf [b][c][n] bf16. Total ~10.7 MB.
// ---------------------------------------------------------------------------
extern "C" void kernel_launch(void* const* d_in, const int* in_sizes, int n_in,
                              void* d_out, int out_size, void* d_ws, size_t ws_size,
                              hipStream_t stream)
{
    const float* x1  = (const float*)d_in[0];
    const float* x2  = (const float*)d_in[1];
    const float* qw  = (const float*)d_in[2];
    const float* qb  = (const float*)d_in[3];
    const float* qg  = (const float*)d_in[4];
    const float* qbe = (const float*)d_in[5];
    const float* qm  = (const float*)d_in[6];
    const float* qv  = (const float*)d_in[7];
    const float* kw  = (const float*)d_in[8];
    const float* kb  = (const float*)d_in[9];
    const float* kg  = (const float*)d_in[10];
    const float* kbe = (const float*)d_in[11];
    const float* km  = (const float*)d_in[12];
    const float* kvv = (const float*)d_in[13];
    const float* vw  = (const float*)d_in[14];
    const float* vb  = (const float*)d_in[15];
    const float* vg  = (const float*)d_in[16];
    const float* vbe = (const float*)d_in[17];
    const float* vm  = (const float*)d_in[18];
    const float* vv  = (const float*)d_in[19];

    char* ws = (char*)d_ws;
    unsigned short* wq   = (unsigned short*)(ws + 0);
    float*          scale= (float*)(ws + 163840);
    float*          off  = (float*)(ws + 165120);
    unsigned short* q_t  = (unsigned short*)(ws + 166400);
    unsigned short* k_t  = (unsigned short*)(ws + 166400 + 1048576);
    unsigned short* v_bf = (unsigned short*)(ws + 166400 + 2097152);

    prep_kernel<<<320, 64, 0, stream>>>(qw, qb, qg, qbe, qm, qv,
                                        kw, kb, kg, kbe, km, kvv,
                                        vw, vb, vg, vbe, vm, vv,
                                        wq, scale, off);
    proj_kernel<<<768, 256, 0, stream>>>(x1, x2, wq, scale, off, q_t, k_t, v_bf);
    flash_kernel<<<512, 256, 0, stream>>>(q_t, k_t, v_bf, (float*)d_out);
}